// Round 9
// baseline (358.826 us; speedup 1.0000x reference)
//
#include <hip/hip_runtime.h>
#include <hip/hip_bf16.h>

typedef _Float16 fp16_t;
typedef __attribute__((ext_vector_type(8))) _Float16 fp16x8;
typedef __attribute__((ext_vector_type(4))) _Float16 fp16x4;
typedef __attribute__((ext_vector_type(4))) float fx4;

#define GLDS(g, l)                                                              \
  __builtin_amdgcn_global_load_lds(                                             \
      (const __attribute__((address_space(1))) void*)(g),                       \
      (__attribute__((address_space(3))) void*)(l), 16, 0, 0)

enum { EPI_F32 = 0, EPI_F16 = 1, EPI_FUSE = 2, EPI_SOFT = 3 };

// ---------------------------------------------------------------------------
// XCD-aware block remap. Requires gridDim.y*gridDim.z divisible by 8.
// ---------------------------------------------------------------------------
__device__ __forceinline__ void xcd_decode(int& bx, int& by, int& bz) {
  const int nx = gridDim.x, ny = gridDim.y;
  const int lid = (int)(blockIdx.x + nx * (blockIdx.y + ny * blockIdx.z));
  const int j = lid & 7, k = lid >> 3;
  bx = k % nx;
  const int s = j + 8 * (k / nx);
  by = s % ny;
  bz = s / ny;
}

// ---------------------------------------------------------------------------
// BT-layout fp16 GEMM: C = A·B^T
// A: [M,K] row-major lda, B: [N,K] row-major ldb.
// Tile 256x128, 8 waves (4M x 2N, each wave 64x64).
// K-loop: TRIPLE-buffered 32-K steps with counted vmcnt (T3/T4):
//   step s: {vmcnt(3) [own buf-s loads done]; s_barrier [all waves done];
//            stage buf (s+2)%3; ds_read+MFMA buf s%3}
// Loads are issued 2 compute-phases before their wait -> the vmcnt wait is
// ~free and prefetch stays in flight ACROSS barriers (no vmcnt(0) drain in
// the steady state). Hazards: buf-ready = per-wave vmcnt + barrier;
// overwrite = stage(s+2)%3==(s-1)%3 issued after the step-s barrier, and all
// reads of that buffer (step s-1) retired before any wave passed it.
// LDS 72KB (+4KB soft) -> 2 blocks/CU preserved.
// EPI_SOFT: tile-local softmax epilogue, register-lean (per-row streaming).
// ---------------------------------------------------------------------------
template <int EPI>
__global__ __launch_bounds__(512) void gemm_bt(
    const fp16_t* __restrict__ A1, const fp16_t* __restrict__ B1,
    void* __restrict__ Cv, int K, int lda, int ldb, long long sA,
    long long sB, long long sC, const float* __restrict__ bias,
    const float* __restrict__ resid, float* __restrict__ m_out,
    float* __restrict__ l_out) {
  __shared__ __align__(16) fp16_t As[3][256 * 32];
  __shared__ __align__(16) fp16_t Bs[3][128 * 32];
  __shared__ float smax[(EPI == EPI_SOFT) ? 512 : 1];
  __shared__ float ssum[(EPI == EPI_SOFT) ? 512 : 1];

  const int tid  = threadIdx.x;
  const int lane = tid & 63;
  const int w    = tid >> 6;   // 0..7
  const int wr   = w >> 1;     // 0..3 (64-row band)
  const int wc   = w & 1;      // 0..1 (64-col band)

  int bx, by, bz;
  xcd_decode(bx, by, bz);
  const int N = (int)gridDim.x * 128;
  const long long tile_m = (long long)by * 256;
  const long long tile_n = (long long)bx * 128;
  const long long z = bz;
  const long long aoff = z * sA + tile_m * (long long)lda;
  const long long boff = z * sB + tile_n * (long long)ldb;

  fx4 acc[4][4];
#pragma unroll
  for (int i = 0; i < 4; i++)
#pragma unroll
    for (int j = 0; j < 4; j++) acc[i][j] = (fx4){0.f, 0.f, 0.f, 0.f};

  // staging swizzle: LDS slot m holds global chunk (m+(r>>1))&3 of row r.
  const int r_l = lane >> 2;
  const int c_l = ((((lane & 3) + ((r_l >> 1) & 3)) & 3) << 3);
  const int frow = lane & 15;
  const int qoff = (((lane >> 4) - ((frow >> 1) & 3)) & 3) << 3;

  const size_t sa0 = (size_t)(w * 16 + r_l) * lda + c_l;
  const size_t sa1 = (size_t)(128 + w * 16 + r_l) * lda + c_l;
  const size_t sb0 = (size_t)(w * 16 + r_l) * ldb + c_l;
  const int ld0 = (w * 16) * 32;
  const int ld1 = (128 + w * 16) * 32;

  auto stage = [&](int b, int kk) {  // 3 GLDS
    const fp16_t* gah = A1 + aoff + kk;
    const fp16_t* gbh = B1 + boff + kk;
    GLDS(gah + sa0, &As[b][ld0]);
    GLDS(gah + sa1, &As[b][ld1]);
    GLDS(gbh + sb0, &Bs[b][ld0]);
  };
  auto compute = [&](int b) {  // 8 ds_read_b128 + 16 MFMA
    fp16x8 afh[4], bbh[4];
#pragma unroll
    for (int mi = 0; mi < 4; mi++)
      afh[mi] = *(const fp16x8*)&As[b][(wr * 64 + mi * 16 + frow) * 32 + qoff];
#pragma unroll
    for (int ni = 0; ni < 4; ni++)
      bbh[ni] = *(const fp16x8*)&Bs[b][(wc * 64 + ni * 16 + frow) * 32 + qoff];
#pragma unroll
    for (int mi = 0; mi < 4; mi++)
#pragma unroll
      for (int ni = 0; ni < 4; ni++)
        acc[mi][ni] = __builtin_amdgcn_mfma_f32_16x16x32_f16(
            afh[mi], bbh[ni], acc[mi][ni], 0, 0, 0);
  };

  const int NS = K >> 5;  // 32-K steps; all our K are % 64 == 0, NS >= 24
  stage(0, 0);
  stage(1, 32);
  int bsel = 0;
  for (int s = 0; s < NS; s++) {
    if (s + 1 < NS) asm volatile("s_waitcnt vmcnt(3)" ::: "memory");
    else            asm volatile("s_waitcnt vmcnt(0)" ::: "memory");
    __builtin_amdgcn_s_barrier();
    __builtin_amdgcn_sched_barrier(0);
    if (s + 2 < NS) {
      int bn = bsel + 2;
      if (bn >= 3) bn -= 3;
      stage(bn, (s + 2) << 5);
    }
    compute(bsel);
    bsel = (bsel + 1 == 3) ? 0 : bsel + 1;
  }

  // Epilogue. C/D layout: col = lane&15, row = (lane>>4)*4 + reg  [m89/m91]
  const int er = (lane >> 4) * 4;
  const int ec = lane & 15;
  const long long crow = tile_m + wr * 64;
  const long long ccol = tile_n + wc * 64;

  if constexpr (EPI == EPI_SOFT) {
    // pass 1: mask diagonal + per-row max (streaming, no arrays)
#pragma unroll
    for (int mi = 0; mi < 4; mi++)
#pragma unroll
      for (int j = 0; j < 4; j++) {
        const long long r = crow + mi * 16 + er + j;
        float mx = -1e30f;
#pragma unroll
        for (int ni = 0; ni < 4; ni++) {
          const long long cc = ccol + ni * 16 + ec;
          float v = acc[mi][ni][j];
          if (r == cc) v = -1e30f;
          acc[mi][ni][j] = v;
          mx = fmaxf(mx, v);
        }
#pragma unroll
        for (int o = 1; o < 16; o <<= 1) mx = fmaxf(mx, __shfl_xor(mx, o, 64));
        if (ec == 0) smax[wc * 256 + wr * 64 + mi * 16 + er + j] = mx;
      }
    __syncthreads();
    // pass 2: exp + per-row sum + P' store (streaming)
#pragma unroll
    for (int mi = 0; mi < 4; mi++)
#pragma unroll
      for (int j = 0; j < 4; j++) {
        const int rid = wr * 64 + mi * 16 + er + j;
        const float m = fmaxf(smax[rid], smax[256 + rid]);
        const long long r = crow + mi * 16 + er + j;
        float s = 0.f;
#pragma unroll
        for (int ni = 0; ni < 4; ni++) {
          const float e = __expf(acc[mi][ni][j] - m);  // diag -> 0
          s += e;
          ((fp16_t*)Cv)[z * sC + r * N + (ccol + ni * 16 + ec)] = (fp16_t)e;
        }
#pragma unroll
        for (int o = 1; o < 16; o <<= 1) s += __shfl_xor(s, o, 64);
        if (ec == 0) ssum[wc * 256 + rid] = s;
      }
    __syncthreads();
    if (tid < 256) {
      const long long si = (z * 16 + bx) * 2048 + tile_m + tid;
      m_out[si] = fmaxf(smax[tid], smax[256 + tid]);
      l_out[si] = ssum[tid] + ssum[256 + tid];
    }
  } else {
#pragma unroll
    for (int mi = 0; mi < 4; mi++)
#pragma unroll
      for (int j = 0; j < 4; j++) {
        const long long r = crow + mi * 16 + er + j;
#pragma unroll
        for (int ni = 0; ni < 4; ni++) {
          const long long cc = ccol + ni * 16 + ec;
          const long long idx = z * sC + r * N + cc;
          const float v = acc[mi][ni][j];
          if (EPI == EPI_F32) {
            ((float*)Cv)[idx] = v;
          } else if (EPI == EPI_F16) {
            ((fp16_t*)Cv)[idx] = (fp16_t)v;
          } else {  // EPI_FUSE
            float u = v + bias[cc];
            u = u > 0.f ? u : 0.f;
            ((float*)Cv)[idx] = resid[r * N + cc] + u;
          }
        }
      }
  }
}

// ---------------------------------------------------------------------------
// PV GEMM: c[m,d] = sum_t scale[m, t/128] * P'[m,t] * xT[d,t]
// 256x128 tile / 8 waves. Same triple-buffered counted-vmcnt K-loop as
// gemm_bt. Scale applied on the A-fragment after ds_read; scale table held
// in LDS as fp16 (8KB) so total LDS = 80KB -> 2 blocks/CU.
// Prologue merges per-tile stats (softmerge fused). Grid (6,8,8). K=2048.
// ---------------------------------------------------------------------------
__global__ __launch_bounds__(512) void gemm_pv(
    const fp16_t* __restrict__ P, const float* __restrict__ mstat,
    const float* __restrict__ lstat, const fp16_t* __restrict__ Bx,
    fp16_t* __restrict__ C) {
  __shared__ __align__(16) fp16_t As[3][256 * 32];
  __shared__ __align__(16) fp16_t Bs[3][128 * 32];
  __shared__ fp16_t sch[16][256];

  const int tid  = threadIdx.x;
  const int lane = tid & 63;
  const int w    = tid >> 6;
  const int wr   = w >> 1;
  const int wc   = w & 1;

  int bx, by, bz;
  xcd_decode(bx, by, bz);
  const long long tile_m = (long long)by * 256;
  const long long tile_n = (long long)bx * 128;
  const long long z = bz;

  // fused softmerge: sch[t][row] = fp16(exp(m_t - m) / l) for block's rows
  if (tid < 256) {
    const long long base = z * 16 * 2048 + tile_m + tid;
    float mv[16];
    float m = -1e30f;
#pragma unroll
    for (int t = 0; t < 16; t++) {
      mv[t] = mstat[base + t * 2048];
      m = fmaxf(m, mv[t]);
    }
    float l = 0.f;
#pragma unroll
    for (int t = 0; t < 16; t++) l += lstat[base + t * 2048] * __expf(mv[t] - m);
    const float il = 1.0f / l;
#pragma unroll
    for (int t = 0; t < 16; t++)
      sch[t][tid] = (fp16_t)(__expf(mv[t] - m) * il);
  }
  __syncthreads();  // sch visible to all waves before any compute

  fx4 acc[4][4];
#pragma unroll
  for (int i = 0; i < 4; i++)
#pragma unroll
    for (int j = 0; j < 4; j++) acc[i][j] = (fx4){0.f, 0.f, 0.f, 0.f};

  // staging swizzle (identical to gemm_bt), lda = ldb = 2048
  const int r_l = lane >> 2;
  const int c_l = ((((lane & 3) + ((r_l >> 1) & 3)) & 3) << 3);
  const int frow = lane & 15;
  const int qoff = (((lane >> 4) - ((frow >> 1) & 3)) & 3) << 3;
  const size_t s0 = (size_t)(w * 16 + r_l) * 2048 + c_l;
  const size_t s1 = (size_t)(128 + w * 16 + r_l) * 2048 + c_l;
  const int ld0 = (w * 16) * 32;
  const int ld1 = (128 + w * 16) * 32;

  const fp16_t* A = P + z * (2048LL * 2048) + tile_m * 2048;
  const fp16_t* B = Bx + z * (768LL * 2048) + tile_n * 2048;

  auto stage = [&](int b, int kk) {  // 3 GLDS
    GLDS(A + kk + s0, &As[b][ld0]);
    GLDS(A + kk + s1, &As[b][ld1]);
    GLDS(B + kk + s0, &Bs[b][ld0]);
  };
  auto compute = [&](int b, const fp16_t* sh) {
    fp16x8 af[4], bb[4];
#pragma unroll
    for (int mi = 0; mi < 4; mi++) {
      af[mi] = *(const fp16x8*)&As[b][(wr * 64 + mi * 16 + frow) * 32 + qoff];
      af[mi] *= sh[mi];
    }
#pragma unroll
    for (int ni = 0; ni < 4; ni++)
      bb[ni] = *(const fp16x8*)&Bs[b][(wc * 64 + ni * 16 + frow) * 32 + qoff];
#pragma unroll
    for (int mi = 0; mi < 4; mi++)
#pragma unroll
      for (int ni = 0; ni < 4; ni++)
        acc[mi][ni] = __builtin_amdgcn_mfma_f32_16x16x32_f16(
            af[mi], bb[ni], acc[mi][ni], 0, 0, 0);
  };

  const int NS = 64;  // 2048 / 32
  stage(0, 0);
  stage(1, 32);
  int bsel = 0;
  for (int s = 0; s < NS; s++) {
    if (s + 1 < NS) asm volatile("s_waitcnt vmcnt(3)" ::: "memory");
    else            asm volatile("s_waitcnt vmcnt(0)" ::: "memory");
    __builtin_amdgcn_s_barrier();
    __builtin_amdgcn_sched_barrier(0);
    if (s + 2 < NS) {
      int bn = bsel + 2;
      if (bn >= 3) bn -= 3;
      stage(bn, (s + 2) << 5);
    }
    // per-row softmax scale; scale tile = 128 cols = 4 steps
    fp16_t sh[4];
    {
      const int tt = s >> 2;
#pragma unroll
      for (int mi = 0; mi < 4; mi++)
        sh[mi] = sch[tt][wr * 64 + mi * 16 + frow];
    }
    compute(bsel, sh);
    bsel = (bsel + 1 == 3) ? 0 : bsel + 1;
  }

  const int er = (lane >> 4) * 4;
  const int ec = lane & 15;
  const long long crow = tile_m + wr * 64;
  const long long ccol = tile_n + wc * 64;
  fp16_t* Cz = C + z * (2048LL * 768);
#pragma unroll
  for (int mi = 0; mi < 4; mi++)
#pragma unroll
    for (int j = 0; j < 4; j++) {
      const long long rr = crow + mi * 16 + er + j;
#pragma unroll
      for (int ni = 0; ni < 4; ni++)
        Cz[rr * 768 + ccol + ni * 16 + ec] = (fp16_t)acc[mi][ni][j];
    }
}

// ---------------------------------------------------------------------------
// Fused prep: x fp32 -> xhl (rows [hi(768) | lo(768)], lda 1536) + xT (hi,
// transposed). The hi half of xhl doubles as the former xh (ldb=1536 views).
// ---------------------------------------------------------------------------
__global__ __launch_bounds__(256) void prep_x(
    const float* __restrict__ x, fp16_t* __restrict__ xhl,
    fp16_t* __restrict__ xT) {
  __shared__ fp16_t t[32][33];
  const int b = blockIdx.z;
  const int d0 = blockIdx.x * 32;
  const int s0 = blockIdx.y * 32;
  const float* ib = x + (long long)b * 2048 * 768;
  const int tx = threadIdx.x & 31;
  const int ty = threadIdx.x >> 5;
#pragma unroll
  for (int i = 0; i < 4; i++) {
    const int srow = s0 + ty + i * 8;
    const float v = ib[(long long)srow * 768 + d0 + tx];
    const fp16_t h = (fp16_t)v;
    const long long rbase = ((long long)b * 2048 + srow) * 1536;
    xhl[rbase + d0 + tx] = h;
    xhl[rbase + 768 + d0 + tx] = (fp16_t)(v - (float)h);
    t[ty + i * 8][tx] = h;
  }
  __syncthreads();
#pragma unroll
  for (int i = 0; i < 4; i++)
    xT[(long long)b * 768 * 2048 + (long long)(d0 + ty + i * 8) * 2048 + s0 + tx] =
        t[tx][ty + i * 8];
}

// ---------------------------------------------------------------------------
// Weight prep: W -> Whh (fp16, [768, 1536], each row = [W_n | W_n]) and
// pw -> ph (fp16, [768,768]). blockIdx.y selects the tensor.
// ---------------------------------------------------------------------------
__global__ __launch_bounds__(256) void cast_w(
    const float* __restrict__ W, const float* __restrict__ pw,
    fp16_t* __restrict__ Whh, fp16_t* __restrict__ ph, int n4) {
  const int i = blockIdx.x * 256 + threadIdx.x;
  if (i >= n4) return;
  if (blockIdx.y == 0) {
    const float4 v = ((const float4*)W)[i];
    const fp16x4 h = {(fp16_t)v.x, (fp16_t)v.y, (fp16_t)v.z, (fp16_t)v.w};
    const int e = i * 4;
    const long long o = (long long)(e / 768) * 1536 + (e % 768);
    *(fp16x4*)&Whh[o] = h;
    *(fp16x4*)&Whh[o + 768] = h;
  } else {
    const float4 v = ((const float4*)pw)[i];
    ((fp16x4*)ph)[i] =
        (fp16x4){(fp16_t)v.x, (fp16_t)v.y, (fp16_t)v.z, (fp16_t)v.w};
  }
}

// ---------------------------------------------------------------------------
extern "C" void kernel_launch(void* const* d_in, const int* in_sizes, int n_in,
                              void* d_out, int out_size, void* d_ws,
                              size_t ws_size, hipStream_t stream) {
  const float* x  = (const float*)d_in[0];
  const float* W  = (const float*)d_in[1];
  const float* pw = (const float*)d_in[2];
  const float* pb = (const float*)d_in[3];

  const long long S = 2048, D = 768;
  const long long BS = 8 * S;

  // ---- workspace (~173 MB) ----
  char* p = (char*)d_ws;
  auto carve = [&](long long bytes) {
    char* q = p;
    p += (bytes + 255) & ~255LL;
    return q;
  };
  fp16_t* xhl = (fp16_t*)carve(BS * 1536 * 2);   // x [hi|lo]      50.3 MB
  fp16_t* xT = (fp16_t*)carve(BS * D * 2);       // x^T (hi)       25.2 MB
  fp16_t* Wx = (fp16_t*)carve(BS * D * 2);       // Wx fp16 / c    25.2 MB
  fp16_t* Whh = (fp16_t*)carve(D * 1536 * 2);    // [W|W] fp16      2.3 MB
  fp16_t* ph = (fp16_t*)carve(D * D * 2);        // proj_w fp16     1.2 MB
  float*  mstat = (float*)carve(BS * 16 * 4);    // per-tile max    1.0 MB
  float*  lstat = (float*)carve(BS * 16 * 4);    // per-tile sum    1.0 MB
  fp16_t* Ps = (fp16_t*)carve(8 * S * S * 2);    // P' fp16        67.1 MB
  fp16_t* cb = Wx;  // c aliases Wx: Wx fully consumed by GEMM2 before PV

  // ---- prep ----
  prep_x<<<dim3(24, 64, 8), 256, 0, stream>>>(x, xhl, xT);
  cast_w<<<dim3((unsigned)(D * D / 4 / 256), 2), 256, 0, stream>>>(
      W, pw, Whh, ph, (int)(D * D / 4));

  // GEMM1: Wx = [xh|xl] @ [W|W]^T  (K=1536, plain GEMM), fp16 out
  gemm_bt<EPI_F16><<<dim3(6, 64, 1), 512, 0, stream>>>(
      xhl, Whh, Wx, 1536, 1536, 1536, 0, 0, 0, nullptr, nullptr, nullptr,
      nullptr);

  // GEMM2 + tile-softmax: P' = exp(s - m_tile) fp16, stats m_t/l_t
  // B = hi half of xhl (ldb = 1536, cols < 768)
  gemm_bt<EPI_SOFT><<<dim3(16, 8, 8), 512, 0, stream>>>(
      Wx, xhl, Ps, 768, 768, 1536, S * D, S * 1536, S * S, nullptr, nullptr,
      mstat, lstat);

  // PV: c = (merged-scale ⊙ P') @ x  ==  A · (xT)^T, K = 2048
  gemm_pv<<<dim3(6, 8, 8), 512, 0, stream>>>(Ps, mstat, lstat, xT, cb);

  // GEMM4: out = x + relu(c @ proj_w^T + pb), fp32
  gemm_bt<EPI_FUSE><<<dim3(6, 64, 1), 512, 0, stream>>>(
      cb, ph, (float*)d_out, 768, 768, 768, 0, 0, 0, pb, x, nullptr,
      nullptr);
}

// Round 10
// 348.656 us; speedup vs baseline: 1.0292x; 1.0292x over previous
//
#include <hip/hip_runtime.h>
#include <hip/hip_bf16.h>

typedef _Float16 fp16_t;
typedef __attribute__((ext_vector_type(8))) _Float16 fp16x8;
typedef __attribute__((ext_vector_type(4))) _Float16 fp16x4;
typedef __attribute__((ext_vector_type(4))) float fx4;

#define GLDS(g, l)                                                              \
  __builtin_amdgcn_global_load_lds(                                             \
      (const __attribute__((address_space(1))) void*)(g),                       \
      (__attribute__((address_space(3))) void*)(l), 16, 0, 0)

enum { EPI_F32 = 0, EPI_F16 = 1, EPI_FUSE = 2, EPI_SOFT = 3 };

// ---------------------------------------------------------------------------
// XCD-aware block remap. Requires gridDim.y*gridDim.z divisible by 8.
// ---------------------------------------------------------------------------
__device__ __forceinline__ void xcd_decode(int& bx, int& by, int& bz) {
  const int nx = gridDim.x, ny = gridDim.y;
  const int lid = (int)(blockIdx.x + nx * (blockIdx.y + ny * blockIdx.z));
  const int j = lid & 7, k = lid >> 3;
  bx = k % nx;
  const int s = j + 8 * (k / nx);
  by = s % ny;
  bz = s / ny;
}

// ---------------------------------------------------------------------------
// BT-layout fp16 GEMM: C = A·B^T
// A: [M,K] row-major lda, B: [N,K] row-major ldb.
// Tile 256x128, 8 waves (4M x 2N, each wave 64x64). Twin-halves BK=64:
// both 32-wide halves staged per barrier pair -> 2x FLOPs per drain,
// 0.75x GLDS per FLOP vs the 128-tile version. LDS 52KB -> 3 blocks/CU
// (r9 lesson: LDS growth costs a resident block and loses; keep 52KB).
// Former hi/lo ASPLIT GEMM1 expressed as plain K=1536 GEMM over interleaved
// [hi|lo] rows and duplicated [W|W] weights.
// T5: s_setprio(1) around the MFMA cluster — with 2-3 independent blocks
// per CU there is wave role diversity for the scheduler to arbitrate.
// EPI_SOFT: tile-local softmax epilogue, register-lean (per-row streaming).
// ---------------------------------------------------------------------------
template <int EPI>
__global__ __launch_bounds__(512) void gemm_bt(
    const fp16_t* __restrict__ A1, const fp16_t* __restrict__ B1,
    void* __restrict__ Cv, int K, int lda, int ldb, long long sA,
    long long sB, long long sC, const float* __restrict__ bias,
    const float* __restrict__ resid, float* __restrict__ m_out,
    float* __restrict__ l_out) {
  __shared__ __align__(16) fp16_t As[2][256 * 32];
  __shared__ __align__(16) fp16_t Bs[2][128 * 32];
  __shared__ float smax[(EPI == EPI_SOFT) ? 512 : 1];
  __shared__ float ssum[(EPI == EPI_SOFT) ? 512 : 1];

  const int tid  = threadIdx.x;
  const int lane = tid & 63;
  const int w    = tid >> 6;   // 0..7
  const int wr   = w >> 1;     // 0..3 (64-row band)
  const int wc   = w & 1;      // 0..1 (64-col band)

  int bx, by, bz;
  xcd_decode(bx, by, bz);
  const int N = (int)gridDim.x * 128;
  const long long tile_m = (long long)by * 256;
  const long long tile_n = (long long)bx * 128;
  const long long z = bz;
  const long long aoff = z * sA + tile_m * (long long)lda;
  const long long boff = z * sB + tile_n * (long long)ldb;

  fx4 acc[4][4];
#pragma unroll
  for (int i = 0; i < 4; i++)
#pragma unroll
    for (int j = 0; j < 4; j++) acc[i][j] = (fx4){0.f, 0.f, 0.f, 0.f};

  // staging swizzle: LDS slot m holds global chunk (m+(r>>1))&3 of row r.
  const int r_l = lane >> 2;
  const int c_l = ((((lane & 3) + ((r_l >> 1) & 3)) & 3) << 3);
  const int frow = lane & 15;
  const int qoff = (((lane >> 4) - ((frow >> 1) & 3)) & 3) << 3;

  const size_t sa0 = (size_t)(w * 16 + r_l) * lda + c_l;
  const size_t sa1 = (size_t)(128 + w * 16 + r_l) * lda + c_l;
  const size_t sb0 = (size_t)(w * 16 + r_l) * ldb + c_l;
  const int ld0 = (w * 16) * 32;
  const int ld1 = (128 + w * 16) * 32;

  auto stage = [&](int h, int kk) {
    const fp16_t* gah = A1 + aoff + kk;
    const fp16_t* gbh = B1 + boff + kk;
    GLDS(gah + sa0, &As[h][ld0]);
    GLDS(gah + sa1, &As[h][ld1]);
    GLDS(gbh + sb0, &Bs[h][ld0]);
  };
  auto compute = [&](int h) {
    fp16x8 afh[4], bbh[4];
#pragma unroll
    for (int mi = 0; mi < 4; mi++)
      afh[mi] = *(const fp16x8*)&As[h][(wr * 64 + mi * 16 + frow) * 32 + qoff];
#pragma unroll
    for (int ni = 0; ni < 4; ni++)
      bbh[ni] = *(const fp16x8*)&Bs[h][(wc * 64 + ni * 16 + frow) * 32 + qoff];
    __builtin_amdgcn_s_setprio(1);
#pragma unroll
    for (int mi = 0; mi < 4; mi++)
#pragma unroll
      for (int ni = 0; ni < 4; ni++)
        acc[mi][ni] = __builtin_amdgcn_mfma_f32_16x16x32_f16(
            afh[mi], bbh[ni], acc[mi][ni], 0, 0, 0);
    __builtin_amdgcn_s_setprio(0);
  };

  for (int kt = 0; kt < K; kt += 64) {
    __syncthreads();
    stage(0, kt);
    stage(1, kt + 32);
    __syncthreads();
    compute(0);
    compute(1);
  }

  // Epilogue. C/D layout: col = lane&15, row = (lane>>4)*4 + reg  [m89/m91]
  const int er = (lane >> 4) * 4;
  const int ec = lane & 15;
  const long long crow = tile_m + wr * 64;
  const long long ccol = tile_n + wc * 64;

  if constexpr (EPI == EPI_SOFT) {
    // pass 1: mask diagonal + per-row max (streaming, no arrays)
#pragma unroll
    for (int mi = 0; mi < 4; mi++)
#pragma unroll
      for (int j = 0; j < 4; j++) {
        const long long r = crow + mi * 16 + er + j;
        float mx = -1e30f;
#pragma unroll
        for (int ni = 0; ni < 4; ni++) {
          const long long cc = ccol + ni * 16 + ec;
          float v = acc[mi][ni][j];
          if (r == cc) v = -1e30f;
          acc[mi][ni][j] = v;
          mx = fmaxf(mx, v);
        }
#pragma unroll
        for (int o = 1; o < 16; o <<= 1) mx = fmaxf(mx, __shfl_xor(mx, o, 64));
        if (ec == 0) smax[wc * 256 + wr * 64 + mi * 16 + er + j] = mx;
      }
    __syncthreads();
    // pass 2: exp + per-row sum + P' store (streaming)
#pragma unroll
    for (int mi = 0; mi < 4; mi++)
#pragma unroll
      for (int j = 0; j < 4; j++) {
        const int rid = wr * 64 + mi * 16 + er + j;
        const float m = fmaxf(smax[rid], smax[256 + rid]);
        const long long r = crow + mi * 16 + er + j;
        float s = 0.f;
#pragma unroll
        for (int ni = 0; ni < 4; ni++) {
          const float e = __expf(acc[mi][ni][j] - m);  // diag -> 0
          s += e;
          ((fp16_t*)Cv)[z * sC + r * N + (ccol + ni * 16 + ec)] = (fp16_t)e;
        }
#pragma unroll
        for (int o = 1; o < 16; o <<= 1) s += __shfl_xor(s, o, 64);
        if (ec == 0) ssum[wc * 256 + rid] = s;
      }
    __syncthreads();
    if (tid < 256) {
      const long long si = (z * 16 + bx) * 2048 + tile_m + tid;
      m_out[si] = fmaxf(smax[tid], smax[256 + tid]);
      l_out[si] = ssum[tid] + ssum[256 + tid];
    }
  } else {
#pragma unroll
    for (int mi = 0; mi < 4; mi++)
#pragma unroll
      for (int j = 0; j < 4; j++) {
        const long long r = crow + mi * 16 + er + j;
#pragma unroll
        for (int ni = 0; ni < 4; ni++) {
          const long long cc = ccol + ni * 16 + ec;
          const long long idx = z * sC + r * N + cc;
          const float v = acc[mi][ni][j];
          if (EPI == EPI_F32) {
            ((float*)Cv)[idx] = v;
          } else if (EPI == EPI_F16) {
            ((fp16_t*)Cv)[idx] = (fp16_t)v;
          } else {  // EPI_FUSE
            float u = v + bias[cc];
            u = u > 0.f ? u : 0.f;
            ((float*)Cv)[idx] = resid[r * N + cc] + u;
          }
        }
      }
  }
}

// ---------------------------------------------------------------------------
// PV GEMM: c[m,d] = sum_t scale[m, t/128] * P'[m,t] * xT[d,t]
// 256x128 tile / 8 waves, same structure as gemm_bt. GLDS staging both
// operands; scale applied on the A-fragment after ds_read (row fixed per
// (lane,mi); each 32-K-step lies inside one 128-col scale tile).
// Prologue merges per-tile stats (softmerge fused). Grid (6,8,8). K=2048.
// ---------------------------------------------------------------------------
__global__ __launch_bounds__(512) void gemm_pv(
    const fp16_t* __restrict__ P, const float* __restrict__ mstat,
    const float* __restrict__ lstat, const fp16_t* __restrict__ Bx,
    fp16_t* __restrict__ C) {
  __shared__ __align__(16) fp16_t As[2][256 * 32];
  __shared__ __align__(16) fp16_t Bs[2][128 * 32];
  __shared__ float sc[16][256];

  const int tid  = threadIdx.x;
  const int lane = tid & 63;
  const int w    = tid >> 6;
  const int wr   = w >> 1;
  const int wc   = w & 1;

  int bx, by, bz;
  xcd_decode(bx, by, bz);
  const long long tile_m = (long long)by * 256;
  const long long tile_n = (long long)bx * 128;
  const long long z = bz;

  // fused softmerge: sc[t][row] = exp(m_t - m) / l  for this block's rows
  if (tid < 256) {
    const long long base = z * 16 * 2048 + tile_m + tid;
    float mv[16];
    float m = -1e30f;
#pragma unroll
    for (int t = 0; t < 16; t++) {
      mv[t] = mstat[base + t * 2048];
      m = fmaxf(m, mv[t]);
    }
    float l = 0.f;
#pragma unroll
    for (int t = 0; t < 16; t++) l += lstat[base + t * 2048] * __expf(mv[t] - m);
    const float il = 1.0f / l;
#pragma unroll
    for (int t = 0; t < 16; t++) sc[t][tid] = __expf(mv[t] - m) * il;
  }

  fx4 acc[4][4];
#pragma unroll
  for (int i = 0; i < 4; i++)
#pragma unroll
    for (int j = 0; j < 4; j++) acc[i][j] = (fx4){0.f, 0.f, 0.f, 0.f};

  // staging swizzle (identical to gemm_bt), lda = ldb = 2048
  const int r_l = lane >> 2;
  const int c_l = ((((lane & 3) + ((r_l >> 1) & 3)) & 3) << 3);
  const int frow = lane & 15;
  const int qoff = (((lane >> 4) - ((frow >> 1) & 3)) & 3) << 3;
  const size_t s0 = (size_t)(w * 16 + r_l) * 2048 + c_l;
  const size_t s1 = (size_t)(128 + w * 16 + r_l) * 2048 + c_l;
  const int ld0 = (w * 16) * 32;
  const int ld1 = (128 + w * 16) * 32;

  const fp16_t* A = P + z * (2048LL * 2048) + tile_m * 2048;
  const fp16_t* B = Bx + z * (768LL * 2048) + tile_n * 2048;

  auto stage = [&](int h, int kk) {
    GLDS(A + kk + s0, &As[h][ld0]);
    GLDS(A + kk + s1, &As[h][ld1]);
    GLDS(B + kk + s0, &Bs[h][ld0]);
  };
  auto compute = [&](int h, const fp16_t* sh) {
    fp16x8 af[4], bb[4];
#pragma unroll
    for (int mi = 0; mi < 4; mi++) {
      af[mi] = *(const fp16x8*)&As[h][(wr * 64 + mi * 16 + frow) * 32 + qoff];
      af[mi] *= sh[mi];
    }
#pragma unroll
    for (int ni = 0; ni < 4; ni++)
      bb[ni] = *(const fp16x8*)&Bs[h][(wc * 64 + ni * 16 + frow) * 32 + qoff];
    __builtin_amdgcn_s_setprio(1);
#pragma unroll
    for (int mi = 0; mi < 4; mi++)
#pragma unroll
      for (int ni = 0; ni < 4; ni++)
        acc[mi][ni] = __builtin_amdgcn_mfma_f32_16x16x32_f16(
            af[mi], bb[ni], acc[mi][ni], 0, 0, 0);
    __builtin_amdgcn_s_setprio(0);
  };

  for (int kt = 0; kt < 2048; kt += 64) {
    __syncthreads();  // first iter: also guards sc[] writes
    stage(0, kt);
    stage(1, kt + 32);
    __syncthreads();
    fp16_t sh[4];
    {
      const int tt = kt >> 7;
#pragma unroll
      for (int mi = 0; mi < 4; mi++)
        sh[mi] = (fp16_t)sc[tt][wr * 64 + mi * 16 + frow];
    }
    compute(0, sh);
    compute(1, sh);
  }

  const int er = (lane >> 4) * 4;
  const int ec = lane & 15;
  const long long crow = tile_m + wr * 64;
  const long long ccol = tile_n + wc * 64;
  fp16_t* Cz = C + z * (2048LL * 768);
#pragma unroll
  for (int mi = 0; mi < 4; mi++)
#pragma unroll
    for (int j = 0; j < 4; j++) {
      const long long rr = crow + mi * 16 + er + j;
#pragma unroll
      for (int ni = 0; ni < 4; ni++)
        Cz[rr * 768 + ccol + ni * 16 + ec] = (fp16_t)acc[mi][ni][j];
    }
}

// ---------------------------------------------------------------------------
// Fused prep: x fp32 -> xhl (rows [hi(768) | lo(768)], lda 1536) + xT (hi,
// transposed). The hi half of xhl doubles as the former xh (ldb=1536 views).
// ---------------------------------------------------------------------------
__global__ __launch_bounds__(256) void prep_x(
    const float* __restrict__ x, fp16_t* __restrict__ xhl,
    fp16_t* __restrict__ xT) {
  __shared__ fp16_t t[32][33];
  const int b = blockIdx.z;
  const int d0 = blockIdx.x * 32;
  const int s0 = blockIdx.y * 32;
  const float* ib = x + (long long)b * 2048 * 768;
  const int tx = threadIdx.x & 31;
  const int ty = threadIdx.x >> 5;
#pragma unroll
  for (int i = 0; i < 4; i++) {
    const int srow = s0 + ty + i * 8;
    const float v = ib[(long long)srow * 768 + d0 + tx];
    const fp16_t h = (fp16_t)v;
    const long long rbase = ((long long)b * 2048 + srow) * 1536;
    xhl[rbase + d0 + tx] = h;
    xhl[rbase + 768 + d0 + tx] = (fp16_t)(v - (float)h);
    t[ty + i * 8][tx] = h;
  }
  __syncthreads();
#pragma unroll
  for (int i = 0; i < 4; i++)
    xT[(long long)b * 768 * 2048 + (long long)(d0 + ty + i * 8) * 2048 + s0 + tx] =
        t[tx][ty + i * 8];
}

// ---------------------------------------------------------------------------
// Weight prep: W -> Whh (fp16, [768, 1536], each row = [W_n | W_n]) and
// pw -> ph (fp16, [768,768]). blockIdx.y selects the tensor.
// ---------------------------------------------------------------------------
__global__ __launch_bounds__(256) void cast_w(
    const float* __restrict__ W, const float* __restrict__ pw,
    fp16_t* __restrict__ Whh, fp16_t* __restrict__ ph, int n4) {
  const int i = blockIdx.x * 256 + threadIdx.x;
  if (i >= n4) return;
  if (blockIdx.y == 0) {
    const float4 v = ((const float4*)W)[i];
    const fp16x4 h = {(fp16_t)v.x, (fp16_t)v.y, (fp16_t)v.z, (fp16_t)v.w};
    const int e = i * 4;
    const long long o = (long long)(e / 768) * 1536 + (e % 768);
    *(fp16x4*)&Whh[o] = h;
    *(fp16x4*)&Whh[o + 768] = h;
  } else {
    const float4 v = ((const float4*)pw)[i];
    ((fp16x4*)ph)[i] =
        (fp16x4){(fp16_t)v.x, (fp16_t)v.y, (fp16_t)v.z, (fp16_t)v.w};
  }
}

// ---------------------------------------------------------------------------
extern "C" void kernel_launch(void* const* d_in, const int* in_sizes, int n_in,
                              void* d_out, int out_size, void* d_ws,
                              size_t ws_size, hipStream_t stream) {
  const float* x  = (const float*)d_in[0];
  const float* W  = (const float*)d_in[1];
  const float* pw = (const float*)d_in[2];
  const float* pb = (const float*)d_in[3];

  const long long S = 2048, D = 768;
  const long long BS = 8 * S;

  // ---- workspace (~173 MB) ----
  char* p = (char*)d_ws;
  auto carve = [&](long long bytes) {
    char* q = p;
    p += (bytes + 255) & ~255LL;
    return q;
  };
  fp16_t* xhl = (fp16_t*)carve(BS * 1536 * 2);   // x [hi|lo]      50.3 MB
  fp16_t* xT = (fp16_t*)carve(BS * D * 2);       // x^T (hi)       25.2 MB
  fp16_t* Wx = (fp16_t*)carve(BS * D * 2);       // Wx fp16 / c    25.2 MB
  fp16_t* Whh = (fp16_t*)carve(D * 1536 * 2);    // [W|W] fp16      2.3 MB
  fp16_t* ph = (fp16_t*)carve(D * D * 2);        // proj_w fp16     1.2 MB
  float*  mstat = (float*)carve(BS * 16 * 4);    // per-tile max    1.0 MB
  float*  lstat = (float*)carve(BS * 16 * 4);    // per-tile sum    1.0 MB
  fp16_t* Ps = (fp16_t*)carve(8 * S * S * 2);    // P' fp16        67.1 MB
  fp16_t* cb = Wx;  // c aliases Wx: Wx fully consumed by GEMM2 before PV

  // ---- prep ----
  prep_x<<<dim3(24, 64, 8), 256, 0, stream>>>(x, xhl, xT);
  cast_w<<<dim3((unsigned)(D * D / 4 / 256), 2), 256, 0, stream>>>(
      W, pw, Whh, ph, (int)(D * D / 4));

  // GEMM1: Wx = [xh|xl] @ [W|W]^T  (K=1536, plain GEMM), fp16 out
  gemm_bt<EPI_F16><<<dim3(6, 64, 1), 512, 0, stream>>>(
      xhl, Whh, Wx, 1536, 1536, 1536, 0, 0, 0, nullptr, nullptr, nullptr,
      nullptr);

  // GEMM2 + tile-softmax: P' = exp(s - m_tile) fp16, stats m_t/l_t
  // B = hi half of xhl (ldb = 1536, cols < 768)
  gemm_bt<EPI_SOFT><<<dim3(16, 8, 8), 512, 0, stream>>>(
      Wx, xhl, Ps, 768, 768, 1536, S * D, S * 1536, S * S, nullptr, nullptr,
      mstat, lstat);

  // PV: c = (merged-scale ⊙ P') @ x  ==  A · (xT)^T, K = 2048
  gemm_pv<<<dim3(6, 8, 8), 512, 0, stream>>>(Ps, mstat, lstat, xT, cb);

  // GEMM4: out = x + relu(c @ proj_w^T + pb), fp32
  gemm_bt<EPI_FUSE><<<dim3(6, 64, 1), 512, 0, stream>>>(
      cb, ph, (float*)d_out, 768, 768, 768, 0, 0, 0, pb, x, nullptr,
      nullptr);
}

// Round 11
// 332.245 us; speedup vs baseline: 1.0800x; 1.0494x over previous
//
#include <hip/hip_runtime.h>
#include <hip/hip_bf16.h>

typedef _Float16 fp16_t;
typedef __attribute__((ext_vector_type(8))) _Float16 fp16x8;
typedef __attribute__((ext_vector_type(4))) _Float16 fp16x4;
typedef __attribute__((ext_vector_type(4))) float fx4;

#define GLDS(g, l)                                                              \
  __builtin_amdgcn_global_load_lds(                                             \
      (const __attribute__((address_space(1))) void*)(g),                       \
      (__attribute__((address_space(3))) void*)(l), 16, 0, 0)

enum { EPI_F32 = 0, EPI_F16 = 1, EPI_FUSE = 2, EPI_SOFT = 3 };

// ---------------------------------------------------------------------------
// XCD-aware block remap. Requires gridDim.y*gridDim.z divisible by 8.
// ---------------------------------------------------------------------------
__device__ __forceinline__ void xcd_decode(int& bx, int& by, int& bz) {
  const int nx = gridDim.x, ny = gridDim.y;
  const int lid = (int)(blockIdx.x + nx * (blockIdx.y + ny * blockIdx.z));
  const int j = lid & 7, k = lid >> 3;
  bx = k % nx;
  const int s = j + 8 * (k / nx);
  by = s % ny;
  bz = s / ny;
}

// ---------------------------------------------------------------------------
// BT-layout fp16 GEMM: C = A·B^T
// A: [M,K] row-major lda, B: [N,K] row-major ldb.
// Tile 256x128, 8 waves (4M x 2N, each wave 64x64). Twin-halves BK=64:
// both 32-wide halves staged per barrier pair -> 2x FLOPs per drain,
// 0.75x GLDS per FLOP vs the 128-tile version. LDS 52KB -> 3 blocks/CU.
// Session ledger: parametric changes won (BK=64, 256-tile, K-merge);
// sync-structure changes all lost (r5 fence-pin, r6 drain-after-prefetch,
// r9 triple-buffer LDS growth, r10 setprio). This is the verified optimum
// of the 2-barrier template (~670 TF = measured structural ceiling m230/233).
// Former hi/lo ASPLIT GEMM1 expressed as plain K=1536 GEMM over interleaved
// [hi|lo] rows and duplicated [W|W] weights.
// EPI_SOFT: tile-local softmax epilogue, register-lean (per-row streaming).
// ---------------------------------------------------------------------------
template <int EPI>
__global__ __launch_bounds__(512) void gemm_bt(
    const fp16_t* __restrict__ A1, const fp16_t* __restrict__ B1,
    void* __restrict__ Cv, int K, int lda, int ldb, long long sA,
    long long sB, long long sC, const float* __restrict__ bias,
    const float* __restrict__ resid, float* __restrict__ m_out,
    float* __restrict__ l_out) {
  __shared__ __align__(16) fp16_t As[2][256 * 32];
  __shared__ __align__(16) fp16_t Bs[2][128 * 32];
  __shared__ float smax[(EPI == EPI_SOFT) ? 512 : 1];
  __shared__ float ssum[(EPI == EPI_SOFT) ? 512 : 1];

  const int tid  = threadIdx.x;
  const int lane = tid & 63;
  const int w    = tid >> 6;   // 0..7
  const int wr   = w >> 1;     // 0..3 (64-row band)
  const int wc   = w & 1;      // 0..1 (64-col band)

  int bx, by, bz;
  xcd_decode(bx, by, bz);
  const int N = (int)gridDim.x * 128;
  const long long tile_m = (long long)by * 256;
  const long long tile_n = (long long)bx * 128;
  const long long z = bz;
  const long long aoff = z * sA + tile_m * (long long)lda;
  const long long boff = z * sB + tile_n * (long long)ldb;

  fx4 acc[4][4];
#pragma unroll
  for (int i = 0; i < 4; i++)
#pragma unroll
    for (int j = 0; j < 4; j++) acc[i][j] = (fx4){0.f, 0.f, 0.f, 0.f};

  // staging swizzle: LDS slot m holds global chunk (m+(r>>1))&3 of row r.
  const int r_l = lane >> 2;
  const int c_l = ((((lane & 3) + ((r_l >> 1) & 3)) & 3) << 3);
  const int frow = lane & 15;
  const int qoff = (((lane >> 4) - ((frow >> 1) & 3)) & 3) << 3;

  const size_t sa0 = (size_t)(w * 16 + r_l) * lda + c_l;
  const size_t sa1 = (size_t)(128 + w * 16 + r_l) * lda + c_l;
  const size_t sb0 = (size_t)(w * 16 + r_l) * ldb + c_l;
  const int ld0 = (w * 16) * 32;
  const int ld1 = (128 + w * 16) * 32;

  auto stage = [&](int h, int kk) {
    const fp16_t* gah = A1 + aoff + kk;
    const fp16_t* gbh = B1 + boff + kk;
    GLDS(gah + sa0, &As[h][ld0]);
    GLDS(gah + sa1, &As[h][ld1]);
    GLDS(gbh + sb0, &Bs[h][ld0]);
  };
  auto compute = [&](int h) {
    fp16x8 afh[4], bbh[4];
#pragma unroll
    for (int mi = 0; mi < 4; mi++)
      afh[mi] = *(const fp16x8*)&As[h][(wr * 64 + mi * 16 + frow) * 32 + qoff];
#pragma unroll
    for (int ni = 0; ni < 4; ni++)
      bbh[ni] = *(const fp16x8*)&Bs[h][(wc * 64 + ni * 16 + frow) * 32 + qoff];
#pragma unroll
    for (int mi = 0; mi < 4; mi++)
#pragma unroll
      for (int ni = 0; ni < 4; ni++)
        acc[mi][ni] = __builtin_amdgcn_mfma_f32_16x16x32_f16(
            afh[mi], bbh[ni], acc[mi][ni], 0, 0, 0);
  };

  for (int kt = 0; kt < K; kt += 64) {
    __syncthreads();
    stage(0, kt);
    stage(1, kt + 32);
    __syncthreads();
    compute(0);
    compute(1);
  }

  // Epilogue. C/D layout: col = lane&15, row = (lane>>4)*4 + reg  [m89/m91]
  const int er = (lane >> 4) * 4;
  const int ec = lane & 15;
  const long long crow = tile_m + wr * 64;
  const long long ccol = tile_n + wc * 64;

  if constexpr (EPI == EPI_SOFT) {
    // pass 1: mask diagonal + per-row max (streaming, no arrays)
#pragma unroll
    for (int mi = 0; mi < 4; mi++)
#pragma unroll
      for (int j = 0; j < 4; j++) {
        const long long r = crow + mi * 16 + er + j;
        float mx = -1e30f;
#pragma unroll
        for (int ni = 0; ni < 4; ni++) {
          const long long cc = ccol + ni * 16 + ec;
          float v = acc[mi][ni][j];
          if (r == cc) v = -1e30f;
          acc[mi][ni][j] = v;
          mx = fmaxf(mx, v);
        }
#pragma unroll
        for (int o = 1; o < 16; o <<= 1) mx = fmaxf(mx, __shfl_xor(mx, o, 64));
        if (ec == 0) smax[wc * 256 + wr * 64 + mi * 16 + er + j] = mx;
      }
    __syncthreads();
    // pass 2: exp + per-row sum + P' store (streaming)
#pragma unroll
    for (int mi = 0; mi < 4; mi++)
#pragma unroll
      for (int j = 0; j < 4; j++) {
        const int rid = wr * 64 + mi * 16 + er + j;
        const float m = fmaxf(smax[rid], smax[256 + rid]);
        const long long r = crow + mi * 16 + er + j;
        float s = 0.f;
#pragma unroll
        for (int ni = 0; ni < 4; ni++) {
          const float e = __expf(acc[mi][ni][j] - m);  // diag -> 0
          s += e;
          ((fp16_t*)Cv)[z * sC + r * N + (ccol + ni * 16 + ec)] = (fp16_t)e;
        }
#pragma unroll
        for (int o = 1; o < 16; o <<= 1) s += __shfl_xor(s, o, 64);
        if (ec == 0) ssum[wc * 256 + rid] = s;
      }
    __syncthreads();
    if (tid < 256) {
      const long long si = (z * 16 + bx) * 2048 + tile_m + tid;
      m_out[si] = fmaxf(smax[tid], smax[256 + tid]);
      l_out[si] = ssum[tid] + ssum[256 + tid];
    }
  } else {
#pragma unroll
    for (int mi = 0; mi < 4; mi++)
#pragma unroll
      for (int j = 0; j < 4; j++) {
        const long long r = crow + mi * 16 + er + j;
#pragma unroll
        for (int ni = 0; ni < 4; ni++) {
          const long long cc = ccol + ni * 16 + ec;
          const long long idx = z * sC + r * N + cc;
          const float v = acc[mi][ni][j];
          if (EPI == EPI_F32) {
            ((float*)Cv)[idx] = v;
          } else if (EPI == EPI_F16) {
            ((fp16_t*)Cv)[idx] = (fp16_t)v;
          } else {  // EPI_FUSE
            float u = v + bias[cc];
            u = u > 0.f ? u : 0.f;
            ((float*)Cv)[idx] = resid[r * N + cc] + u;
          }
        }
      }
  }
}

// ---------------------------------------------------------------------------
// PV GEMM: c[m,d] = sum_t scale[m, t/128] * P'[m,t] * xT[d,t]
// 256x128 tile / 8 waves, same structure as gemm_bt. GLDS staging both
// operands; scale applied on the A-fragment after ds_read (row fixed per
// (lane,mi); each 32-K-step lies inside one 128-col scale tile).
// Prologue merges per-tile stats (softmerge fused). Grid (6,8,8). K=2048.
// ---------------------------------------------------------------------------
__global__ __launch_bounds__(512) void gemm_pv(
    const fp16_t* __restrict__ P, const float* __restrict__ mstat,
    const float* __restrict__ lstat, const fp16_t* __restrict__ Bx,
    fp16_t* __restrict__ C) {
  __shared__ __align__(16) fp16_t As[2][256 * 32];
  __shared__ __align__(16) fp16_t Bs[2][128 * 32];
  __shared__ float sc[16][256];

  const int tid  = threadIdx.x;
  const int lane = tid & 63;
  const int w    = tid >> 6;
  const int wr   = w >> 1;
  const int wc   = w & 1;

  int bx, by, bz;
  xcd_decode(bx, by, bz);
  const long long tile_m = (long long)by * 256;
  const long long tile_n = (long long)bx * 128;
  const long long z = bz;

  // fused softmerge: sc[t][row] = exp(m_t - m) / l  for this block's rows
  if (tid < 256) {
    const long long base = z * 16 * 2048 + tile_m + tid;
    float mv[16];
    float m = -1e30f;
#pragma unroll
    for (int t = 0; t < 16; t++) {
      mv[t] = mstat[base + t * 2048];
      m = fmaxf(m, mv[t]);
    }
    float l = 0.f;
#pragma unroll
    for (int t = 0; t < 16; t++) l += lstat[base + t * 2048] * __expf(mv[t] - m);
    const float il = 1.0f / l;
#pragma unroll
    for (int t = 0; t < 16; t++) sc[t][tid] = __expf(mv[t] - m) * il;
  }

  fx4 acc[4][4];
#pragma unroll
  for (int i = 0; i < 4; i++)
#pragma unroll
    for (int j = 0; j < 4; j++) acc[i][j] = (fx4){0.f, 0.f, 0.f, 0.f};

  // staging swizzle (identical to gemm_bt), lda = ldb = 2048
  const int r_l = lane >> 2;
  const int c_l = ((((lane & 3) + ((r_l >> 1) & 3)) & 3) << 3);
  const int frow = lane & 15;
  const int qoff = (((lane >> 4) - ((frow >> 1) & 3)) & 3) << 3;
  const size_t s0 = (size_t)(w * 16 + r_l) * 2048 + c_l;
  const size_t s1 = (size_t)(128 + w * 16 + r_l) * 2048 + c_l;
  const int ld0 = (w * 16) * 32;
  const int ld1 = (128 + w * 16) * 32;

  const fp16_t* A = P + z * (2048LL * 2048) + tile_m * 2048;
  const fp16_t* B = Bx + z * (768LL * 2048) + tile_n * 2048;

  auto stage = [&](int h, int kk) {
    GLDS(A + kk + s0, &As[h][ld0]);
    GLDS(A + kk + s1, &As[h][ld1]);
    GLDS(B + kk + s0, &Bs[h][ld0]);
  };
  auto compute = [&](int h, const fp16_t* sh) {
    fp16x8 af[4], bb[4];
#pragma unroll
    for (int mi = 0; mi < 4; mi++) {
      af[mi] = *(const fp16x8*)&As[h][(wr * 64 + mi * 16 + frow) * 32 + qoff];
      af[mi] *= sh[mi];
    }
#pragma unroll
    for (int ni = 0; ni < 4; ni++)
      bb[ni] = *(const fp16x8*)&Bs[h][(wc * 64 + ni * 16 + frow) * 32 + qoff];
#pragma unroll
    for (int mi = 0; mi < 4; mi++)
#pragma unroll
      for (int ni = 0; ni < 4; ni++)
        acc[mi][ni] = __builtin_amdgcn_mfma_f32_16x16x32_f16(
            af[mi], bb[ni], acc[mi][ni], 0, 0, 0);
  };

  for (int kt = 0; kt < 2048; kt += 64) {
    __syncthreads();  // first iter: also guards sc[] writes
    stage(0, kt);
    stage(1, kt + 32);
    __syncthreads();
    fp16_t sh[4];
    {
      const int tt = kt >> 7;
#pragma unroll
      for (int mi = 0; mi < 4; mi++)
        sh[mi] = (fp16_t)sc[tt][wr * 64 + mi * 16 + frow];
    }
    compute(0, sh);
    compute(1, sh);
  }

  const int er = (lane >> 4) * 4;
  const int ec = lane & 15;
  const long long crow = tile_m + wr * 64;
  const long long ccol = tile_n + wc * 64;
  fp16_t* Cz = C + z * (2048LL * 768);
#pragma unroll
  for (int mi = 0; mi < 4; mi++)
#pragma unroll
    for (int j = 0; j < 4; j++) {
      const long long rr = crow + mi * 16 + er + j;
#pragma unroll
      for (int ni = 0; ni < 4; ni++)
        Cz[rr * 768 + ccol + ni * 16 + ec] = (fp16_t)acc[mi][ni][j];
    }
}

// ---------------------------------------------------------------------------
// Fused prep: x fp32 -> xhl (rows [hi(768) | lo(768)], lda 1536) + xT (hi,
// transposed). The hi half of xhl doubles as the former xh (ldb=1536 views).
// ---------------------------------------------------------------------------
__global__ __launch_bounds__(256) void prep_x(
    const float* __restrict__ x, fp16_t* __restrict__ xhl,
    fp16_t* __restrict__ xT) {
  __shared__ fp16_t t[32][33];
  const int b = blockIdx.z;
  const int d0 = blockIdx.x * 32;
  const int s0 = blockIdx.y * 32;
  const float* ib = x + (long long)b * 2048 * 768;
  const int tx = threadIdx.x & 31;
  const int ty = threadIdx.x >> 5;
#pragma unroll
  for (int i = 0; i < 4; i++) {
    const int srow = s0 + ty + i * 8;
    const float v = ib[(long long)srow * 768 + d0 + tx];
    const fp16_t h = (fp16_t)v;
    const long long rbase = ((long long)b * 2048 + srow) * 1536;
    xhl[rbase + d0 + tx] = h;
    xhl[rbase + 768 + d0 + tx] = (fp16_t)(v - (float)h);
    t[ty + i * 8][tx] = h;
  }
  __syncthreads();
#pragma unroll
  for (int i = 0; i < 4; i++)
    xT[(long long)b * 768 * 2048 + (long long)(d0 + ty + i * 8) * 2048 + s0 + tx] =
        t[tx][ty + i * 8];
}

// ---------------------------------------------------------------------------
// Weight prep: W -> Whh (fp16, [768, 1536], each row = [W_n | W_n]) and
// pw -> ph (fp16, [768,768]). blockIdx.y selects the tensor.
// ---------------------------------------------------------------------------
__global__ __launch_bounds__(256) void cast_w(
    const float* __restrict__ W, const float* __restrict__ pw,
    fp16_t* __restrict__ Whh, fp16_t* __restrict__ ph, int n4) {
  const int i = blockIdx.x * 256 + threadIdx.x;
  if (i >= n4) return;
  if (blockIdx.y == 0) {
    const float4 v = ((const float4*)W)[i];
    const fp16x4 h = {(fp16_t)v.x, (fp16_t)v.y, (fp16_t)v.z, (fp16_t)v.w};
    const int e = i * 4;
    const long long o = (long long)(e / 768) * 1536 + (e % 768);
    *(fp16x4*)&Whh[o] = h;
    *(fp16x4*)&Whh[o + 768] = h;
  } else {
    const float4 v = ((const float4*)pw)[i];
    ((fp16x4*)ph)[i] =
        (fp16x4){(fp16_t)v.x, (fp16_t)v.y, (fp16_t)v.z, (fp16_t)v.w};
  }
}

// ---------------------------------------------------------------------------
extern "C" void kernel_launch(void* const* d_in, const int* in_sizes, int n_in,
                              void* d_out, int out_size, void* d_ws,
                              size_t ws_size, hipStream_t stream) {
  const float* x  = (const float*)d_in[0];
  const float* W  = (const float*)d_in[1];
  const float* pw = (const float*)d_in[2];
  const float* pb = (const float*)d_in[3];

  const long long S = 2048, D = 768;
  const long long BS = 8 * S;

  // ---- workspace (~173 MB) ----
  char* p = (char*)d_ws;
  auto carve = [&](long long bytes) {
    char* q = p;
    p += (bytes + 255) & ~255LL;
    return q;
  };
  fp16_t* xhl = (fp16_t*)carve(BS * 1536 * 2);   // x [hi|lo]      50.3 MB
  fp16_t* xT = (fp16_t*)carve(BS * D * 2);       // x^T (hi)       25.2 MB
  fp16_t* Wx = (fp16_t*)carve(BS * D * 2);       // Wx fp16 / c    25.2 MB
  fp16_t* Whh = (fp16_t*)carve(D * 1536 * 2);    // [W|W] fp16      2.3 MB
  fp16_t* ph = (fp16_t*)carve(D * D * 2);        // proj_w fp16     1.2 MB
  float*  mstat = (float*)carve(BS * 16 * 4);    // per-tile max    1.0 MB
  float*  lstat = (float*)carve(BS * 16 * 4);    // per-tile sum    1.0 MB
  fp16_t* Ps = (fp16_t*)carve(8 * S * S * 2);    // P' fp16        67.1 MB
  fp16_t* cb = Wx;  // c aliases Wx: Wx fully consumed by GEMM2 before PV

  // ---- prep ----
  prep_x<<<dim3(24, 64, 8), 256, 0, stream>>>(x, xhl, xT);
  cast_w<<<dim3((unsigned)(D * D / 4 / 256), 2), 256, 0, stream>>>(
      W, pw, Whh, ph, (int)(D * D / 4));

  // GEMM1: Wx = [xh|xl] @ [W|W]^T  (K=1536, plain GEMM), fp16 out
  gemm_bt<EPI_F16><<<dim3(6, 64, 1), 512, 0, stream>>>(
      xhl, Whh, Wx, 1536, 1536, 1536, 0, 0, 0, nullptr, nullptr, nullptr,
      nullptr);

  // GEMM2 + tile-softmax: P' = exp(s - m_tile) fp16, stats m_t/l_t
  // B = hi half of xhl (ldb = 1536, cols < 768)
  gemm_bt<EPI_SOFT><<<dim3(16, 8, 8), 512, 0, stream>>>(
      Wx, xhl, Ps, 768, 768, 1536, S * D, S * 1536, S * S, nullptr, nullptr,
      mstat, lstat);

  // PV: c = (merged-scale ⊙ P') @ x  ==  A · (xT)^T, K = 2048
  gemm_pv<<<dim3(6, 8, 8), 512, 0, stream>>>(Ps, mstat, lstat, xT, cb);

  // GEMM4: out = x + relu(c @ proj_w^T + pb), fp32
  gemm_bt<EPI_FUSE><<<dim3(6, 64, 1), 512, 0, stream>>>(
      cb, ph, (float*)d_out, 768, 768, 768, 0, 0, 0, pb, x, nullptr,
      nullptr);
}